// Round 4
// baseline (380.906 us; speedup 1.0000x reference)
//
#include <hip/hip_runtime.h>
#include <math.h>

#define NROWS 16384
#define NCOLS 1000
#define NMAT  5
#define WPB   4                         // waves (rows) per block
#define BLOCKS_A (NROWS / WPB)          // 4096
#define NINF (-INFINITY)

// ---------------------------------------------------------------------------
// One 64-lane wave per row across all 5 matrices. launch_bounds(256,1) lifts
// the VGPR cap to 512 so the 20-float4 load burst (80 VGPRs) stays LIVE and
// in flight, instead of being serialized by regalloc (R2's VGPR=52 failure).
// Target logit comes from the loaded registers (shuffle broadcast) - no
// dependent global gather tail.
// ---------------------------------------------------------------------------
__global__ __launch_bounds__(256, 1) void fused_kernel(
    const float* __restrict__ o0, const float* __restrict__ o1,
    const float* __restrict__ o2, const float* __restrict__ o3,
    const float* __restrict__ o4, const int* __restrict__ targets,
    float* __restrict__ out, float* __restrict__ blockmax)
{
    const int wave = threadIdx.x >> 6;
    const int lane = threadIdx.x & 63;
    const int row  = blockIdx.x * WPB + wave;

    // Issue early: result only needed after the butterfly.
    const int t     = targets[row];
    const int q     = t >> 2;            // float4 index of target element
    const int comp  = t & 3;
    const int chunk = q >> 6;            // 0..3 (q <= 249 -> srcLane <= 57, valid)
    const int src   = q & 63;

    const float* rows[NMAT];
    rows[0] = o0 + (size_t)row * NCOLS;
    rows[1] = o1 + (size_t)row * NCOLS;
    rows[2] = o2 + (size_t)row * NCOLS;
    rows[3] = o3 + (size_t)row * NCOLS;
    rows[4] = o4 + (size_t)row * NCOLS;

    // 20 float4 loads, all live simultaneously: 20 KB in flight per wave.
    float4 v[NMAT][4];
    #pragma unroll
    for (int m = 0; m < NMAT; ++m) {
        const float4* b = (const float4*)rows[m];
        v[m][0] = b[lane];
        v[m][1] = b[lane + 64];
        v[m][2] = b[lane + 128];
        v[m][3] = make_float4(NINF, NINF, NINF, NINF);
    }
    if (lane < 58) {                     // 250 float4/row; lanes 0..57 take a 4th
        #pragma unroll
        for (int m = 0; m < NMAT; ++m)
            v[m][3] = ((const float4*)rows[m])[lane + 192];
    }

    // Target logits straight from registers: uniform select + shuffle bcast.
    float tgt[NMAT];
    #pragma unroll
    for (int m = 0; m < NMAT; ++m) {
        float4 f = (chunk == 0) ? v[m][0] : (chunk == 1) ? v[m][1]
                 : (chunk == 2) ? v[m][2] : v[m][3];
        float  x = (comp == 0) ? f.x : (comp == 1) ? f.y
                 : (comp == 2) ? f.z : f.w;
        tgt[m] = __shfl(x, src);
    }

    // Per-lane top-2 (branch-free).
    float t1[NMAT], t2[NMAT];
#define UPD(m, x) { float _mn = fminf(t1[m], (x)); t1[m] = fmaxf(t1[m], (x)); \
                    t2[m] = fmaxf(t2[m], _mn); }
    #pragma unroll
    for (int m = 0; m < NMAT; ++m) {
        t1[m] = NINF; t2[m] = NINF;
        #pragma unroll
        for (int c = 0; c < 4; ++c) {
            UPD(m, v[m][c].x) UPD(m, v[m][c].y)
            UPD(m, v[m][c].z) UPD(m, v[m][c].w)
        }
    }
#undef UPD

    // 6-step butterfly, 5 matrices interleaved (10 independent shuffles/step).
    #pragma unroll
    for (int off = 32; off > 0; off >>= 1) {
        float a1[NMAT], a2[NMAT];
        #pragma unroll
        for (int m = 0; m < NMAT; ++m) {
            a1[m] = __shfl_xor(t1[m], off);
            a2[m] = __shfl_xor(t2[m], off);
        }
        #pragma unroll
        for (int m = 0; m < NMAT; ++m) {
            float mn = fminf(t1[m], a1[m]);
            t1[m] = fmaxf(t1[m], a1[m]);
            t2[m] = fmaxf(fmaxf(t2[m], a2[m]), mn);
        }
    }

    // All-lane tail: margins + softmax (no serial lane-0 section).
    float mg[NMAT];
    #pragma unroll
    for (int m = 0; m < NMAT; ++m)
        mg[m] = (tgt[m] == t1[m]) ? (t1[m] - t2[m]) : 0.0f;

    float mx = mg[0];
    #pragma unroll
    for (int m = 1; m < NMAT; ++m) mx = fmaxf(mx, mg[m]);
    float e[NMAT], s = 0.0f;
    #pragma unroll
    for (int m = 0; m < NMAT; ++m) { e[m] = __expf((mg[m] - mx) * 0.5f); s += e[m]; }
    const float inv = 1.0f / s;

    float wv = e[0] * inv;
    if (lane == 1) wv = e[1] * inv;
    if (lane == 2) wv = e[2] * inv;
    if (lane == 3) wv = e[3] * inv;
    if (lane == 4) wv = e[4] * inv;
    if (lane < NMAT) out[1 + (size_t)row * NMAT + lane] = wv;

    // Per-block max over matrices 0..3 (mimic excluded).
    __shared__ float smax[WPB];
    if (lane == 0)
        smax[wave] = fmaxf(fmaxf(t1[0], t1[1]), fmaxf(t1[2], t1[3]));
    __syncthreads();
    if (threadIdx.x == 0)
        blockmax[blockIdx.x] =
            fmaxf(fmaxf(smax[0], smax[1]), fmaxf(smax[2], smax[3]));
}

// ---------------------------------------------------------------------------
// Tiny reduce: 4096 block maxima -> out[0].
// ---------------------------------------------------------------------------
__global__ __launch_bounds__(256) void reduce_kernel(
    const float* __restrict__ blockmax, float* __restrict__ out)
{
    __shared__ float red[256];
    float mm = NINF;
    for (int k = threadIdx.x; k < BLOCKS_A; k += 256)
        mm = fmaxf(mm, blockmax[k]);
    red[threadIdx.x] = mm;
    __syncthreads();
    #pragma unroll
    for (int s = 128; s > 0; s >>= 1) {
        if (threadIdx.x < s)
            red[threadIdx.x] = fmaxf(red[threadIdx.x], red[threadIdx.x + s]);
        __syncthreads();
    }
    if (threadIdx.x == 0) out[0] = red[0];
}

extern "C" void kernel_launch(void* const* d_in, const int* in_sizes, int n_in,
                              void* d_out, int out_size, void* d_ws, size_t ws_size,
                              hipStream_t stream) {
    const float* o0 = (const float*)d_in[0];
    const float* o1 = (const float*)d_in[1];
    const float* o2 = (const float*)d_in[2];
    const float* o3 = (const float*)d_in[3];
    const float* o4 = (const float*)d_in[4];
    const int*   tg = (const int*)d_in[5];
    float* out = (float*)d_out;

    float* blockmax = (float*)d_ws;      // BLOCKS_A floats (16 KB)

    fused_kernel<<<BLOCKS_A, 256, 0, stream>>>(o0, o1, o2, o3, o4, tg,
                                               out, blockmax);
    reduce_kernel<<<1, 256, 0, stream>>>(blockmax, out);
}